// Round 1
// baseline (1647.298 us; speedup 1.0000x reference)
//
#include <hip/hip_runtime.h>
#include <hip/hip_bf16.h>
#include <math.h>

#define D_MODEL    1024
#define EXPERT_DIM 4096
#define N_EXPERTS  8
#define N_TOKENS   4096
#define M_TILE     64
#define MAX_TILES  72

// workspace byte offsets
#define OFF_PROBS   0u          // 4096*8 f32   (131072 B)
#define OFF_EXP     131072u     // 4096 i32
#define OFF_GATE    147456u     // 4096 f32
#define OFF_CNT     163840u     // 8 i32
#define OFF_CUR     163872u     // 8 i32
#define OFF_OFFS    163904u     // 9 i32
#define OFF_NT      163940u     // 1 i32
#define OFF_TE      163968u     // 72 i32
#define OFF_TR      164256u     // 72 i32
#define OFF_BUCKET  164544u     // 4096 i32
#define OFF_H       196608u     // 4096*4096 f32 (64 MiB)

__global__ __launch_bounds__(256) void gate_kernel(
    const float* __restrict__ x, const float* __restrict__ gw,
    float* __restrict__ probs, int* __restrict__ tok_e,
    float* __restrict__ tok_g, int* __restrict__ cnt) {
  int token = (blockIdx.x * blockDim.x + threadIdx.x) >> 6;
  int lane = threadIdx.x & 63;
  if (token >= N_TOKENS) return;
  const float* xr = x + (size_t)token * D_MODEL;
  float xv[16];
#pragma unroll
  for (int i = 0; i < 16; ++i) xv[i] = xr[lane + 64 * i];
  float logit[N_EXPERTS];
#pragma unroll
  for (int e = 0; e < N_EXPERTS; ++e) {
    const float* g = gw + e * D_MODEL;
    float s = 0.f;
#pragma unroll
    for (int i = 0; i < 16; ++i) s = fmaf(xv[i], g[lane + 64 * i], s);
#pragma unroll
    for (int m = 32; m; m >>= 1) s += __shfl_xor(s, m, 64);
    logit[e] = s;
  }
  if (lane == 0) {
    float mx = logit[0]; int arg = 0;
#pragma unroll
    for (int e = 1; e < N_EXPERTS; ++e)
      if (logit[e] > mx) { mx = logit[e]; arg = e; }
    float pe[N_EXPERTS]; float den = 0.f;
#pragma unroll
    for (int e = 0; e < N_EXPERTS; ++e) { pe[e] = __expf(logit[e] - mx); den += pe[e]; }
    float inv = 1.f / den;
#pragma unroll
    for (int e = 0; e < N_EXPERTS; ++e) probs[token * N_EXPERTS + e] = pe[e] * inv;
    tok_e[token] = arg;
    tok_g[token] = pe[arg] * inv;
    atomicAdd(&cnt[arg], 1);
  }
}

__global__ __launch_bounds__(256) void plan_kernel(
    const float* __restrict__ probs, const int* __restrict__ cnt,
    int* __restrict__ offs, int* __restrict__ ntiles,
    int* __restrict__ tile_e, int* __restrict__ tile_r0,
    float* __restrict__ aux_out) {
  __shared__ float red[256];
  __shared__ float simp[N_EXPERTS];
  int t = threadIdx.x;
  for (int e = 0; e < N_EXPERTS; ++e) {
    float s = 0.f;
    for (int n = t; n < N_TOKENS; n += 256) s += probs[n * N_EXPERTS + e];
    red[t] = s; __syncthreads();
    for (int w = 128; w; w >>= 1) {
      if (t < w) red[t] += red[t + w];
      __syncthreads();
    }
    if (t == 0) simp[e] = red[0];
    __syncthreads();
  }
  if (t == 0) {
    int o = 0, nt = 0; float aux = 0.f;
    for (int e = 0; e < N_EXPERTS; ++e) {
      offs[e] = o;
      int c = cnt[e];
      int m = (c + M_TILE - 1) / M_TILE;
      for (int i = 0; i < m; ++i) { tile_e[nt] = e; tile_r0[nt] = i * M_TILE; ++nt; }
      aux += (float)c * simp[e];
      o += c;
    }
    offs[N_EXPERTS] = o;
    *ntiles = nt;
    *aux_out = aux * (1.f / ((float)N_TOKENS * (float)N_TOKENS)) * N_EXPERTS * 0.01f;
  }
}

__global__ __launch_bounds__(256) void scatter_kernel(
    const int* __restrict__ tok_e, int* __restrict__ cursor,
    const int* __restrict__ offs, int* __restrict__ bucket) {
  int n = blockIdx.x * blockDim.x + threadIdx.x;
  if (n >= N_TOKENS) return;
  int e = tok_e[n];
  int p = atomicAdd(&cursor[e], 1);
  bucket[offs[e] + p] = n;
}

// H[base+row, f] = silu(x@w1[e]^T) * (x@w3[e]^T)   64x64 tile, 4x4 micro
__global__ __launch_bounds__(256) void gemm1_kernel(
    const float* __restrict__ x, const float* __restrict__ w1,
    const float* __restrict__ w3, const int* __restrict__ ntiles,
    const int* __restrict__ tile_e, const int* __restrict__ tile_r0,
    const int* __restrict__ offs, const int* __restrict__ bucket,
    float* __restrict__ H) {
  int tile = blockIdx.y;
  if (tile >= *ntiles) return;
  int e = tile_e[tile];
  int r0 = tile_r0[tile];
  int base = offs[e];
  int cnt = offs[e + 1] - base;
  int f0 = blockIdx.x * 64;

  __shared__ float As[16][65];
  __shared__ float B1s[16][64];
  __shared__ float B3s[16][64];

  int t = threadIdx.x;
  int lm = t >> 2;
  int lk = (t & 3) << 2;
  int rowc = min(r0 + lm, cnt - 1);
  int tok = bucket[base + rowc];
  const float* aptr = x + (size_t)tok * D_MODEL + lk;
  const float* b1p = w1 + ((size_t)e * EXPERT_DIM + f0 + lm) * D_MODEL + lk;
  const float* b3p = w3 + ((size_t)e * EXPERT_DIM + f0 + lm) * D_MODEL + lk;

  int tx = t & 15, ty = t >> 4;
  float u[4][4] = {{0.f}}, v[4][4] = {{0.f}};

  for (int k0 = 0; k0 < D_MODEL; k0 += 16) {
    float4 av = *(const float4*)(aptr + k0);
    float4 b1 = *(const float4*)(b1p + k0);
    float4 b3 = *(const float4*)(b3p + k0);
    __syncthreads();
    As[lk + 0][lm] = av.x; As[lk + 1][lm] = av.y;
    As[lk + 2][lm] = av.z; As[lk + 3][lm] = av.w;
    B1s[lk + 0][lm] = b1.x; B1s[lk + 1][lm] = b1.y;
    B1s[lk + 2][lm] = b1.z; B1s[lk + 3][lm] = b1.w;
    B3s[lk + 0][lm] = b3.x; B3s[lk + 1][lm] = b3.y;
    B3s[lk + 2][lm] = b3.z; B3s[lk + 3][lm] = b3.w;
    __syncthreads();
#pragma unroll
    for (int k = 0; k < 16; ++k) {
      float a[4];
#pragma unroll
      for (int i = 0; i < 4; ++i) a[i] = As[k][ty * 4 + i];
      float4 q1 = *(const float4*)&B1s[k][tx * 4];
      float4 q3 = *(const float4*)&B3s[k][tx * 4];
      float b1a[4] = {q1.x, q1.y, q1.z, q1.w};
      float b3a[4] = {q3.x, q3.y, q3.z, q3.w};
#pragma unroll
      for (int i = 0; i < 4; ++i)
#pragma unroll
        for (int j = 0; j < 4; ++j) {
          u[i][j] = fmaf(a[i], b1a[j], u[i][j]);
          v[i][j] = fmaf(a[i], b3a[j], v[i][j]);
        }
    }
  }
#pragma unroll
  for (int i = 0; i < 4; ++i) {
    int rg = r0 + ty * 4 + i;
    if (rg < cnt) {
      float hv[4];
#pragma unroll
      for (int j = 0; j < 4; ++j) {
        float uu = u[i][j];
        float s = uu / (1.f + __expf(-uu));
        hv[j] = s * v[i][j];
      }
      float* hp = H + (size_t)(base + rg) * EXPERT_DIM + f0 + tx * 4;
      *(float4*)hp = make_float4(hv[0], hv[1], hv[2], hv[3]);
    }
  }
}

// out[tok, d] = (H[row] @ w2[e]^T) * gate   64x64 tile
__global__ __launch_bounds__(256) void gemm2_kernel(
    const float* __restrict__ H, const float* __restrict__ w2,
    const int* __restrict__ ntiles, const int* __restrict__ tile_e,
    const int* __restrict__ tile_r0, const int* __restrict__ offs,
    const int* __restrict__ bucket, const float* __restrict__ tok_g,
    float* __restrict__ out) {
  int tile = blockIdx.y;
  if (tile >= *ntiles) return;
  int e = tile_e[tile];
  int r0 = tile_r0[tile];
  int base = offs[e];
  int cnt = offs[e + 1] - base;
  int d0 = blockIdx.x * 64;

  __shared__ float As[16][65];
  __shared__ float Bs[16][64];

  int t = threadIdx.x;
  int lm = t >> 2;
  int lk = (t & 3) << 2;
  int rowc = min(r0 + lm, cnt - 1);
  const float* aptr = H + (size_t)(base + rowc) * EXPERT_DIM + lk;
  const float* bp = w2 + ((size_t)e * D_MODEL + d0 + lm) * EXPERT_DIM + lk;

  int tx = t & 15, ty = t >> 4;
  float acc[4][4] = {{0.f}};

  for (int k0 = 0; k0 < EXPERT_DIM; k0 += 16) {
    float4 av = *(const float4*)(aptr + k0);
    float4 bv = *(const float4*)(bp + k0);
    __syncthreads();
    As[lk + 0][lm] = av.x; As[lk + 1][lm] = av.y;
    As[lk + 2][lm] = av.z; As[lk + 3][lm] = av.w;
    Bs[lk + 0][lm] = bv.x; Bs[lk + 1][lm] = bv.y;
    Bs[lk + 2][lm] = bv.z; Bs[lk + 3][lm] = bv.w;
    __syncthreads();
#pragma unroll
    for (int k = 0; k < 16; ++k) {
      float a[4];
#pragma unroll
      for (int i = 0; i < 4; ++i) a[i] = As[k][ty * 4 + i];
      float4 q = *(const float4*)&Bs[k][tx * 4];
      float ba[4] = {q.x, q.y, q.z, q.w};
#pragma unroll
      for (int i = 0; i < 4; ++i)
#pragma unroll
        for (int j = 0; j < 4; ++j)
          acc[i][j] = fmaf(a[i], ba[j], acc[i][j]);
    }
  }
#pragma unroll
  for (int i = 0; i < 4; ++i) {
    int rg = r0 + ty * 4 + i;
    if (rg < cnt) {
      int tok = bucket[base + rg];
      float g = tok_g[tok];
      float* op = out + (size_t)tok * D_MODEL + d0 + tx * 4;
      *(float4*)op = make_float4(acc[i][0] * g, acc[i][1] * g,
                                 acc[i][2] * g, acc[i][3] * g);
    }
  }
}

extern "C" void kernel_launch(void* const* d_in, const int* in_sizes, int n_in,
                              void* d_out, int out_size, void* d_ws, size_t ws_size,
                              hipStream_t stream) {
  const float* x  = (const float*)d_in[0];
  const float* gw = (const float*)d_in[1];
  const float* w1 = (const float*)d_in[2];
  const float* w2 = (const float*)d_in[3];
  const float* w3 = (const float*)d_in[4];
  float* out = (float*)d_out;
  char* ws = (char*)d_ws;

  float* probs = (float*)(ws + OFF_PROBS);
  int* tok_e   = (int*)(ws + OFF_EXP);
  float* tok_g = (float*)(ws + OFF_GATE);
  int* cnt     = (int*)(ws + OFF_CNT);
  int* cur     = (int*)(ws + OFF_CUR);
  int* offs    = (int*)(ws + OFF_OFFS);
  int* ntiles  = (int*)(ws + OFF_NT);
  int* tile_e  = (int*)(ws + OFF_TE);
  int* tile_r0 = (int*)(ws + OFF_TR);
  int* bucket  = (int*)(ws + OFF_BUCKET);
  float* H     = (float*)(ws + OFF_H);

  hipMemsetAsync(ws + OFF_CNT, 0, 64, stream);  // cnt + cursor
  gate_kernel<<<N_TOKENS / 4, 256, 0, stream>>>(x, gw, probs, tok_e, tok_g, cnt);
  plan_kernel<<<1, 256, 0, stream>>>(probs, cnt, offs, ntiles, tile_e, tile_r0,
                                     out + (size_t)N_TOKENS * D_MODEL);
  scatter_kernel<<<N_TOKENS / 256, 256, 0, stream>>>(tok_e, cur, offs, bucket);
  gemm1_kernel<<<dim3(EXPERT_DIM / 64, MAX_TILES), 256, 0, stream>>>(
      x, w1, w3, ntiles, tile_e, tile_r0, offs, bucket, H);
  gemm2_kernel<<<dim3(D_MODEL / 64, MAX_TILES), 256, 0, stream>>>(
      H, w2, ntiles, tile_e, tile_r0, offs, bucket, tok_g, out);
}

// Round 2
// 376.978 us; speedup vs baseline: 4.3698x; 4.3698x over previous
//
#include <hip/hip_runtime.h>
#include <hip/hip_bf16.h>
#include <math.h>

#define D_MODEL    1024
#define EXPERT_DIM 4096
#define N_EXPERTS  8
#define N_TOKENS   4096
#define M_TILE     128
#define MAX_TILES  40

typedef __attribute__((ext_vector_type(8))) short short8;
typedef __attribute__((ext_vector_type(4))) float f32x4;

// workspace byte offsets
#define OFF_PROBS   0u          // 4096*8 f32
#define OFF_EXP     131072u     // 4096 i32
#define OFF_GATE    147456u     // 4096 f32
#define OFF_CNT     163840u     // 8 i32
#define OFF_CUR     163872u     // 8 i32
#define OFF_OFFS    163904u     // 9 i32
#define OFF_NT      163940u     // 1 i32
#define OFF_TE      164096u     // 40 i32
#define OFF_TR      164352u     // 40 i32
#define OFF_BUCKET  164608u     // 4096 i32
#define OFF_XB      262144u     // 4096*1024 bf16 = 8 MiB
#define OFF_H       8650752u    // 4096*4096 bf16 = 32 MiB  (ends ~40.3 MiB)

#define GLOAD_LDS16(gp, lp) \
  __builtin_amdgcn_global_load_lds((const __attribute__((address_space(1))) void*)(gp), \
                                   (__attribute__((address_space(3))) void*)(lp), 16, 0, 0)

static __device__ __forceinline__ ushort f2b(float f) {
  union { __hip_bfloat16 h; ushort u; } c;
  c.h = __float2bfloat16(f);
  return c.u;
}

static __device__ __forceinline__ short8 pack8(float4 a, float4 b) {
  short8 r;
  r[0] = (short)f2b(a.x); r[1] = (short)f2b(a.y);
  r[2] = (short)f2b(a.z); r[3] = (short)f2b(a.w);
  r[4] = (short)f2b(b.x); r[5] = (short)f2b(b.y);
  r[6] = (short)f2b(b.z); r[7] = (short)f2b(b.w);
  return r;
}

// ---------------- gating (fp32, exact argmax) + x -> bf16 cast ----------------
__global__ __launch_bounds__(256) void gate_kernel(
    const float* __restrict__ x, const float* __restrict__ gw,
    float* __restrict__ probs, int* __restrict__ tok_e,
    float* __restrict__ tok_g, int* __restrict__ cnt,
    ushort* __restrict__ xb) {
  int token = (blockIdx.x * blockDim.x + threadIdx.x) >> 6;
  int lane = threadIdx.x & 63;
  if (token >= N_TOKENS) return;
  const float* xr = x + (size_t)token * D_MODEL;
  float xv[16];
#pragma unroll
  for (int i = 0; i < 16; ++i) xv[i] = xr[lane + 64 * i];
  // emit bf16 copy of x
  ushort* xo = xb + (size_t)token * D_MODEL;
#pragma unroll
  for (int i = 0; i < 16; ++i) xo[lane + 64 * i] = f2b(xv[i]);
  float logit[N_EXPERTS];
#pragma unroll
  for (int e = 0; e < N_EXPERTS; ++e) {
    const float* g = gw + e * D_MODEL;
    float s = 0.f;
#pragma unroll
    for (int i = 0; i < 16; ++i) s = fmaf(xv[i], g[lane + 64 * i], s);
#pragma unroll
    for (int m = 32; m; m >>= 1) s += __shfl_xor(s, m, 64);
    logit[e] = s;
  }
  if (lane == 0) {
    float mx = logit[0]; int arg = 0;
#pragma unroll
    for (int e = 1; e < N_EXPERTS; ++e)
      if (logit[e] > mx) { mx = logit[e]; arg = e; }
    float pe[N_EXPERTS]; float den = 0.f;
#pragma unroll
    for (int e = 0; e < N_EXPERTS; ++e) { pe[e] = __expf(logit[e] - mx); den += pe[e]; }
    float inv = 1.f / den;
#pragma unroll
    for (int e = 0; e < N_EXPERTS; ++e) probs[token * N_EXPERTS + e] = pe[e] * inv;
    tok_e[token] = arg;
    tok_g[token] = pe[arg] * inv;
    atomicAdd(&cnt[arg], 1);
  }
}

__global__ __launch_bounds__(256) void plan_kernel(
    const float* __restrict__ probs, const int* __restrict__ cnt,
    int* __restrict__ offs, int* __restrict__ ntiles,
    int* __restrict__ tile_e, int* __restrict__ tile_r0,
    float* __restrict__ aux_out) {
  __shared__ float red[256];
  __shared__ float simp[N_EXPERTS];
  int t = threadIdx.x;
  for (int e = 0; e < N_EXPERTS; ++e) {
    float s = 0.f;
    for (int n = t; n < N_TOKENS; n += 256) s += probs[n * N_EXPERTS + e];
    red[t] = s; __syncthreads();
    for (int w = 128; w; w >>= 1) {
      if (t < w) red[t] += red[t + w];
      __syncthreads();
    }
    if (t == 0) simp[e] = red[0];
    __syncthreads();
  }
  if (t == 0) {
    int o = 0, nt = 0; float aux = 0.f;
    for (int e = 0; e < N_EXPERTS; ++e) {
      offs[e] = o;
      int c = cnt[e];
      int m = (c + M_TILE - 1) / M_TILE;
      for (int i = 0; i < m; ++i) { tile_e[nt] = e; tile_r0[nt] = i * M_TILE; ++nt; }
      aux += (float)c * simp[e];
      o += c;
    }
    offs[N_EXPERTS] = o;
    *ntiles = nt;
    *aux_out = aux * (1.f / ((float)N_TOKENS * (float)N_TOKENS)) * N_EXPERTS * 0.01f;
  }
}

__global__ __launch_bounds__(256) void scatter_kernel(
    const int* __restrict__ tok_e, int* __restrict__ cursor,
    const int* __restrict__ offs, int* __restrict__ bucket) {
  int n = blockIdx.x * blockDim.x + threadIdx.x;
  if (n >= N_TOKENS) return;
  int e = tok_e[n];
  int p = atomicAdd(&cursor[e], 1);
  bucket[offs[e] + p] = n;
}

// ---- GEMM1: H[base+r, f] = silu(x@w1^T) * (x@w3^T), bf16 MFMA, tile 128x64 ----
__global__ __launch_bounds__(256) void gemm1_kernel(
    const ushort* __restrict__ xb, const float* __restrict__ w1,
    const float* __restrict__ w3, const int* __restrict__ ntiles,
    const int* __restrict__ tile_e, const int* __restrict__ tile_r0,
    const int* __restrict__ offs, const int* __restrict__ bucket,
    ushort* __restrict__ H) {
  int tile = blockIdx.y;
  if (tile >= *ntiles) return;
  int e = tile_e[tile], r0 = tile_r0[tile];
  int base = offs[e], cnt = offs[e + 1] - base;
  int f0 = blockIdx.x * 64;

  __shared__ ushort As[128 * 64];   // tokens x k  (16 KB)
  __shared__ ushort B1s[64 * 64];   // f x k       (8 KB)
  __shared__ ushort B3s[64 * 64];

  int tid = threadIdx.x;
  int w = tid >> 6, lane = tid & 63;
  int wm = w >> 1, wn = w & 1;

  // A staging: wave w covers tile rows w*32 .. w*32+31 in 4 chunks of 8 rows
  const ushort* aptr[4];
#pragma unroll
  for (int c = 0; c < 4; ++c) {
    int r = w * 32 + c * 8 + (lane >> 3);
    int rr = min(r0 + r, cnt - 1);
    int tok = bucket[base + rr];
    aptr[c] = xb + (size_t)tok * D_MODEL + (lane & 7) * 8;
  }
  // B staging: thread covers B row rb (an f index), cols qb*16..+15
  int rb = tid >> 2, qb = tid & 3;
  const float4* p1 = (const float4*)(w1 + ((size_t)e * EXPERT_DIM + f0 + rb) * D_MODEL + qb * 16);
  const float4* p3 = (const float4*)(w3 + ((size_t)e * EXPERT_DIM + f0 + rb) * D_MODEL + qb * 16);
  ushort* wb1 = &B1s[rb * 64 + qb * 16];
  ushort* wb3 = &B3s[rb * 64 + qb * 16];

  f32x4 accU[4][2], accV[4][2];
#pragma unroll
  for (int i = 0; i < 4; ++i)
#pragma unroll
    for (int j = 0; j < 2; ++j) { accU[i][j] = (f32x4)0.f; accV[i][j] = (f32x4)0.f; }

  for (int k0 = 0; k0 < D_MODEL; k0 += 64) {
#pragma unroll
    for (int c = 0; c < 4; ++c)
      GLOAD_LDS16(aptr[c] + k0, &As[(w * 32 + c * 8) * 64]);
    const float4* q1 = p1 + (k0 >> 2);
    const float4* q3 = p3 + (k0 >> 2);
    float4 u0 = q1[0], u1 = q1[1], u2 = q1[2], u3 = q1[3];
    float4 v0 = q3[0], v1 = q3[1], v2 = q3[2], v3 = q3[3];
    *(short8*)wb1       = pack8(u0, u1);
    *(short8*)(wb1 + 8) = pack8(u2, u3);
    *(short8*)wb3       = pack8(v0, v1);
    *(short8*)(wb3 + 8) = pack8(v2, v3);
    __syncthreads();
#pragma unroll
    for (int ks = 0; ks < 2; ++ks) {
      int ko = ks * 32 + (lane >> 4) * 8;
      short8 af[4], bf1[2], bf3[2];
#pragma unroll
      for (int i = 0; i < 4; ++i)
        af[i] = *(const short8*)&As[(wm * 64 + i * 16 + (lane & 15)) * 64 + ko];
#pragma unroll
      for (int j = 0; j < 2; ++j) {
        bf1[j] = *(const short8*)&B1s[(wn * 32 + j * 16 + (lane & 15)) * 64 + ko];
        bf3[j] = *(const short8*)&B3s[(wn * 32 + j * 16 + (lane & 15)) * 64 + ko];
      }
#pragma unroll
      for (int i = 0; i < 4; ++i)
#pragma unroll
        for (int j = 0; j < 2; ++j) {
          accU[i][j] = __builtin_amdgcn_mfma_f32_16x16x32_bf16(af[i], bf1[j], accU[i][j], 0, 0, 0);
          accV[i][j] = __builtin_amdgcn_mfma_f32_16x16x32_bf16(af[i], bf3[j], accV[i][j], 0, 0, 0);
        }
    }
    __syncthreads();
  }
  // epilogue: h = silu(u)*v -> bf16 H
#pragma unroll
  for (int i = 0; i < 4; ++i)
#pragma unroll
    for (int q = 0; q < 4; ++q) {
      int m_loc = wm * 64 + i * 16 + (lane >> 4) * 4 + q;
      if (r0 + m_loc < cnt) {
        size_t rowb = (size_t)(base + r0 + m_loc) * EXPERT_DIM + f0 + wn * 32 + (lane & 15);
#pragma unroll
        for (int j = 0; j < 2; ++j) {
          float uu = accU[i][j][q], vv = accV[i][j][q];
          float h = uu / (1.f + __expf(-uu)) * vv;
          H[rowb + j * 16] = f2b(h);
        }
      }
    }
}

// ---- GEMM2: out[tok, d] = (H @ w2^T) * gate, bf16 MFMA, tile 128x64 ----
__global__ __launch_bounds__(256) void gemm2_kernel(
    const ushort* __restrict__ H, const float* __restrict__ w2,
    const int* __restrict__ ntiles, const int* __restrict__ tile_e,
    const int* __restrict__ tile_r0, const int* __restrict__ offs,
    const int* __restrict__ bucket, const float* __restrict__ tok_g,
    float* __restrict__ out) {
  int tile = blockIdx.y;
  if (tile >= *ntiles) return;
  int e = tile_e[tile], r0 = tile_r0[tile];
  int base = offs[e], cnt = offs[e + 1] - base;
  int d0 = blockIdx.x * 64;

  __shared__ ushort As[128 * 64];
  __shared__ ushort Bs[64 * 64];

  int tid = threadIdx.x;
  int w = tid >> 6, lane = tid & 63;
  int wm = w >> 1, wn = w & 1;

  const ushort* aptr[4];
#pragma unroll
  for (int c = 0; c < 4; ++c) {
    int r = w * 32 + c * 8 + (lane >> 3);
    int rr = min(r0 + r, cnt - 1);
    aptr[c] = H + (size_t)(base + rr) * EXPERT_DIM + (lane & 7) * 8;
  }
  int rb = tid >> 2, qb = tid & 3;
  const float4* p2 = (const float4*)(w2 + ((size_t)e * D_MODEL + d0 + rb) * EXPERT_DIM + qb * 16);
  ushort* wb = &Bs[rb * 64 + qb * 16];

  f32x4 acc[4][2];
#pragma unroll
  for (int i = 0; i < 4; ++i)
#pragma unroll
    for (int j = 0; j < 2; ++j) acc[i][j] = (f32x4)0.f;

  for (int k0 = 0; k0 < EXPERT_DIM; k0 += 64) {
#pragma unroll
    for (int c = 0; c < 4; ++c)
      GLOAD_LDS16(aptr[c] + k0, &As[(w * 32 + c * 8) * 64]);
    const float4* q = p2 + (k0 >> 2);
    float4 u0 = q[0], u1 = q[1], u2 = q[2], u3 = q[3];
    *(short8*)wb       = pack8(u0, u1);
    *(short8*)(wb + 8) = pack8(u2, u3);
    __syncthreads();
#pragma unroll
    for (int ks = 0; ks < 2; ++ks) {
      int ko = ks * 32 + (lane >> 4) * 8;
      short8 af[4], bf[2];
#pragma unroll
      for (int i = 0; i < 4; ++i)
        af[i] = *(const short8*)&As[(wm * 64 + i * 16 + (lane & 15)) * 64 + ko];
#pragma unroll
      for (int j = 0; j < 2; ++j)
        bf[j] = *(const short8*)&Bs[(wn * 32 + j * 16 + (lane & 15)) * 64 + ko];
#pragma unroll
      for (int i = 0; i < 4; ++i)
#pragma unroll
        for (int j = 0; j < 2; ++j)
          acc[i][j] = __builtin_amdgcn_mfma_f32_16x16x32_bf16(af[i], bf[j], acc[i][j], 0, 0, 0);
    }
    __syncthreads();
  }
#pragma unroll
  for (int i = 0; i < 4; ++i)
#pragma unroll
    for (int q = 0; q < 4; ++q) {
      int m_loc = wm * 64 + i * 16 + (lane >> 4) * 4 + q;
      if (r0 + m_loc < cnt) {
        int tok = bucket[base + r0 + m_loc];
        float g = tok_g[tok];
        float* op = out + (size_t)tok * D_MODEL + d0 + wn * 32 + (lane & 15);
#pragma unroll
        for (int j = 0; j < 2; ++j)
          op[j * 16] = acc[i][j][q] * g;
      }
    }
}

extern "C" void kernel_launch(void* const* d_in, const int* in_sizes, int n_in,
                              void* d_out, int out_size, void* d_ws, size_t ws_size,
                              hipStream_t stream) {
  const float* x  = (const float*)d_in[0];
  const float* gw = (const float*)d_in[1];
  const float* w1 = (const float*)d_in[2];
  const float* w2 = (const float*)d_in[3];
  const float* w3 = (const float*)d_in[4];
  float* out = (float*)d_out;
  char* ws = (char*)d_ws;

  float* probs = (float*)(ws + OFF_PROBS);
  int* tok_e   = (int*)(ws + OFF_EXP);
  float* tok_g = (float*)(ws + OFF_GATE);
  int* cnt     = (int*)(ws + OFF_CNT);
  int* cur     = (int*)(ws + OFF_CUR);
  int* offs    = (int*)(ws + OFF_OFFS);
  int* ntiles  = (int*)(ws + OFF_NT);
  int* tile_e  = (int*)(ws + OFF_TE);
  int* tile_r0 = (int*)(ws + OFF_TR);
  int* bucket  = (int*)(ws + OFF_BUCKET);
  ushort* xb   = (ushort*)(ws + OFF_XB);
  ushort* H    = (ushort*)(ws + OFF_H);

  hipMemsetAsync(ws + OFF_CNT, 0, 64, stream);  // cnt + cursor
  gate_kernel<<<N_TOKENS / 4, 256, 0, stream>>>(x, gw, probs, tok_e, tok_g, cnt, xb);
  plan_kernel<<<1, 256, 0, stream>>>(probs, cnt, offs, ntiles, tile_e, tile_r0,
                                     out + (size_t)N_TOKENS * D_MODEL);
  scatter_kernel<<<N_TOKENS / 256, 256, 0, stream>>>(tok_e, cur, offs, bucket);
  gemm1_kernel<<<dim3(EXPERT_DIM / 64, MAX_TILES), 256, 0, stream>>>(
      xb, w1, w3, ntiles, tile_e, tile_r0, offs, bucket, H);
  gemm2_kernel<<<dim3(D_MODEL / 64, MAX_TILES), 256, 0, stream>>>(
      H, w2, ntiles, tile_e, tile_r0, offs, bucket, tok_g, out);
}